// Round 9
// baseline (149.204 us; speedup 1.0000x reference)
//
#include <hip/hip_runtime.h>
#include <math.h>

#define IMG_H 4096
#define IMG_W 4096
#define TS 64
#define HALO 3
#define TW 70              // TS + 2*HALO rows
#define THS 76             // th row stride (words): 76%32=12 -> 2-way only; 76*4%16==0
#define HMS 68             // hm row stride (words): 68%32=4  -> 2-way only; aligned
#define NBINS 4096         // fallback: linear value bins over [-4, 4]
#define CBLK 1024          // count_compact grid blocks
#define CAPA 1024          // per-block candidate staging (expected ~26/block)
#define CAND_MAX (1u<<22)  // candA capacity
// speculative window: sample median of 16.7M N(0,1) is 0 +- 3.1e-4 (1 sigma);
// [-1/512, +1/512) covers +-6.3 sigma. Exact single-kernel fallback guards it.
#define WLO (-0.001953125f)
#define WHI ( 0.001953125f)
#define RSLOT 32           // finalize register slots/thread (32k cand cap)
#define MCAP 1024          // member buffer for the selected sub-bin
#define NSUB 2048          // linear sub-bins across the window

struct SelState {
    unsigned bin;
    unsigned k_rem;
    float    median;
    unsigned flag;   // ALWAYS written by finalize (no memset dependence)
};

__device__ __forceinline__ unsigned f2u(float f) {
    unsigned b = __float_as_uint(f);
    unsigned mask = (unsigned)(-(int)(b >> 31)) | 0x80000000u;
    return b ^ mask;
}
__device__ __forceinline__ float u2f(unsigned u) {
    unsigned mask = (u >> 31) ? 0x80000000u : 0xFFFFFFFFu;
    return __uint_as_float(u ^ mask);
}

// fallback-only: monotone value->bin map
__device__ __forceinline__ int val_bin(float v) {
    float t = (v + 4.0f) * 512.0f;
    int b = (int)t;
    b = b < 0 ? 0 : b;
    b = b > (NBINS - 1) ? (NBINS - 1) : b;
    return b;
}

// sub-bin map over the window [WLO, WHI)
__device__ __forceinline__ int sub_bin(float v) {
    float t = (v - WLO) * (float)(NSUB * 256);
    int b = (int)t;
    b = b < 0 ? 0 : b;
    b = b > (NSUB - 1) ? (NSUB - 1) : b;
    return b;
}

// ONE full read: register count of (x < WLO) + LDS-staged compaction of
// window candidates (one global atomic per block).
__global__ __launch_bounds__(512) void count_compact(
    const float4* __restrict__ x4, int n4,
    unsigned* __restrict__ belowArr,      // [CBLK], plain stores
    unsigned* __restrict__ candA, unsigned* __restrict__ cntA)
{
    __shared__ unsigned buf[CAPA];
    __shared__ unsigned wred[8];
    __shared__ unsigned lcnt, gbase;
    const int t = threadIdx.x;
    if (t == 0) lcnt = 0;
    __syncthreads();

    unsigned below = 0;
    int idx = blockIdx.x * 512 + t;
    int stride = gridDim.x * 512;
    for (int i = idx; i < n4; i += stride) {
        float4 v = x4[i];
        float vs[4] = {v.x, v.y, v.z, v.w};
        #pragma unroll
        for (int j = 0; j < 4; j++) {
            float vv = vs[j];
            below += (vv < WLO) ? 1u : 0u;
            if (vv >= WLO && vv < WHI) {
                unsigned p = atomicAdd(&lcnt, 1u);
                unsigned key = f2u(vv);
                if (p < CAPA) buf[p] = key;
                else { unsigned q = atomicAdd(cntA, 1u); if (q < CAND_MAX) candA[q] = key; }
            }
        }
    }
    #pragma unroll
    for (int off = 32; off >= 1; off >>= 1) below += __shfl_down(below, off, 64);
    if ((t & 63) == 0) wred[t >> 6] = below;
    __syncthreads();
    if (t == 0) {
        unsigned tot = 0;
        #pragma unroll
        for (int w = 0; w < 8; w++) tot += wred[w];
        belowArr[blockIdx.x] = tot;
        gbase = atomicAdd(cntA, (lcnt > CAPA) ? CAPA : lcnt);
    }
    __syncthreads();
    unsigned m = lcnt; if (m > CAPA) m = CAPA;
    for (unsigned i = t; i < m; i += 512) {
        unsigned q = gbase + i;
        if (q < CAND_MAX) candA[q] = buf[i];
    }
}

// Single block, 1024 threads: sum belowArr; if K lands in the candidate set,
// select exactly via register-resident candidates + linear sub-bin histogram.
// ALWAYS writes st->flag (and median iff flag=1).
__global__ __launch_bounds__(1024) void finalize_kernel(
    const unsigned* __restrict__ belowArr,
    const unsigned* __restrict__ candA, const unsigned* __restrict__ cntA,
    unsigned K, SelState* __restrict__ st)
{
    __shared__ unsigned hist[NSUB];
    __shared__ unsigned mem[MCAP];
    __shared__ unsigned wsum[16];
    __shared__ unsigned s_below, s_sb, s_kr2, mcnt, s_found;
    __shared__ float s_med;
    const int t = threadIdx.x;
    const unsigned lane = t & 63, wid = t >> 6;

    unsigned b = (t < CBLK) ? belowArr[t] : 0u;
    #pragma unroll
    for (int off = 32; off >= 1; off >>= 1) b += __shfl_down(b, off, 64);
    if (lane == 0) wsum[wid] = b;
    if (t == 0) { mcnt = 0; s_found = 0; }
    __syncthreads();
    if (t == 0) {
        unsigned tot = 0;
        #pragma unroll
        for (int w = 0; w < 16; w++) tot += wsum[w];
        s_below = tot;
    }
    __syncthreads();

    const unsigned below = s_below;
    const unsigned M = *cntA;
    const bool direct = (K >= below) && (K - below < M) && (M <= RSLOT * 1024u);
    if (!direct) {
        if (t == 0) st->flag = 0;
        return;
    }

    const unsigned kRem = K - below;

    // load all candidates into registers (one streaming burst)
    unsigned rc[RSLOT];
    #pragma unroll
    for (int j = 0; j < RSLOT; j++) {
        int i = j * 1024 + t;
        rc[j] = (i < (int)M) ? candA[i] : 0u;
    }
    for (int i = t; i < NSUB; i += 1024) hist[i] = 0;
    __syncthreads();

    // linear sub-bin histogram (near-uniform -> cheap LDS atomics)
    #pragma unroll
    for (int j = 0; j < RSLOT; j++) {
        int i = j * 1024 + t;
        if (i < (int)M) atomicAdd(&hist[sub_bin(u2f(rc[j]))], 1u);
    }
    __syncthreads();

    // scan sub-bins (2/thread)
    unsigned d0 = hist[t * 2], d1 = hist[t * 2 + 1];
    unsigned loc2 = d0 + d1;
    unsigned s2 = loc2;
    #pragma unroll
    for (int off = 1; off < 64; off <<= 1) {
        unsigned u = __shfl_up(s2, off, 64);
        if (lane >= off) s2 += u;
    }
    if (lane == 63) wsum[wid] = s2;
    __syncthreads();
    unsigned base2 = 0;
    for (unsigned w = 0; w < wid; w++) base2 += wsum[w];
    unsigned excl2 = base2 + s2 - loc2;
    if (kRem >= excl2 && kRem < excl2 + loc2) {
        if (kRem < excl2 + d0) { s_sb = (unsigned)(t * 2);     s_kr2 = kRem - excl2; }
        else                   { s_sb = (unsigned)(t * 2 + 1); s_kr2 = kRem - excl2 - d0; }
    }
    __syncthreads();

    // gather members of the selected sub-bin
    const int sb = (int)s_sb;
    #pragma unroll
    for (int j = 0; j < RSLOT; j++) {
        int i = j * 1024 + t;
        if (i < (int)M && sub_bin(u2f(rc[j])) == sb) {
            unsigned p = atomicAdd(&mcnt, 1u);
            if (p < MCAP) mem[p] = rc[j];
        }
    }
    __syncthreads();

    if (mcnt <= MCAP) {
        // O(m^2) rank-count select among m members (m ~ 13)
        const unsigned m = mcnt;
        const unsigned kr2 = s_kr2;
        if ((unsigned)t < m) {
            unsigned ku = mem[t];
            unsigned c = 0, e = 0;
            for (unsigned j = 0; j < m; j++) {
                unsigned kj = mem[j];
                c += (kj < ku);
                e += (kj == ku);
            }
            if (c <= kr2 && kr2 < c + e) { s_med = u2f(ku); s_found = 1; }
        }
    }
    __syncthreads();
    if (t == 0) {
        if (s_found) st->median = s_med;
        st->flag = s_found;      // 0 => exact fallback runs
    }
}

// ---- exact fallback, ONE single-block kernel (runs fully only if flag==0) --
// Slow but exact for ANY input distribution; in practice: one flag load.
__global__ __launch_bounds__(1024) void fb_exact(
    const float4* __restrict__ x4, int n4, unsigned K,
    unsigned* __restrict__ candB, SelState* __restrict__ st)
{
    if (st->flag) return;
    __shared__ unsigned lh[NBINS];
    __shared__ unsigned wsum[16];
    __shared__ unsigned s_bin, s_krem, s_m, s_pref, s_kr;
    const int t = threadIdx.x;
    const unsigned lane = t & 63, wid = t >> 6;

    for (int i = t; i < NBINS; i += 1024) lh[i] = 0;
    __syncthreads();
    for (int i = t; i < n4; i += 1024) {
        float4 v = x4[i];
        atomicAdd(&lh[val_bin(v.x)], 1u);
        atomicAdd(&lh[val_bin(v.y)], 1u);
        atomicAdd(&lh[val_bin(v.z)], 1u);
        atomicAdd(&lh[val_bin(v.w)], 1u);
    }
    __syncthreads();

    {
        unsigned cb[4];
        unsigned local = 0;
        #pragma unroll
        for (int j = 0; j < 4; j++) { cb[j] = lh[t * 4 + j]; local += cb[j]; }
        unsigned s = local;
        #pragma unroll
        for (int off = 1; off < 64; off <<= 1) {
            unsigned u = __shfl_up(s, off, 64);
            if (lane >= off) s += u;
        }
        if (lane == 63) wsum[wid] = s;
        __syncthreads();
        unsigned base = 0;
        for (unsigned w = 0; w < wid; w++) base += wsum[w];
        unsigned excl = base + s - local;
        if (K >= excl && K < excl + local) {
            unsigned cum = excl;
            #pragma unroll
            for (int j = 0; j < 4; j++) {
                if (K < cum + cb[j]) { s_bin = (unsigned)(t * 4 + j); s_krem = K - cum; break; }
                cum += cb[j];
            }
        }
        if (t == 0) s_m = 0;
        __syncthreads();
    }

    {
        const int b = (int)s_bin;
        for (int i = t; i < n4; i += 1024) {
            float4 v = x4[i];
            float vs[4] = {v.x, v.y, v.z, v.w};
            #pragma unroll
            for (int j = 0; j < 4; j++) {
                if (val_bin(vs[j]) == b) {
                    unsigned p = atomicAdd(&s_m, 1u);
                    candB[p] = f2u(vs[j]);
                }
            }
        }
        __syncthreads();
    }

    const int M = (int)s_m;
    if (t == 0) { s_pref = 0; s_kr = s_krem; }
    for (int p = 0; p < 3; p++) {
        const int shift = (p == 0) ? 21 : ((p == 1) ? 10 : 0);
        const int bits  = (p == 2) ? 10 : 11;
        const int nb    = 1 << bits;
        for (int i = t; i < nb; i += 1024) lh[i] = 0;
        __syncthreads();
        const unsigned pref = s_pref;
        for (int i = t; i < M; i += 1024) {
            unsigned u = candB[i];
            bool ok = (p == 0) || ((u >> ((p == 1) ? 21 : 10)) == pref);
            if (ok) atomicAdd(&lh[(u >> shift) & (unsigned)(nb - 1)], 1u);
        }
        __syncthreads();
        const int P = nb >> 10;           // 2 or 1 bins/thread
        unsigned c0 = (P == 2) ? lh[t * 2] : lh[t];
        unsigned c1 = (P == 2) ? lh[t * 2 + 1] : 0u;
        unsigned local = c0 + c1;
        unsigned s = local;
        #pragma unroll
        for (int off = 1; off < 64; off <<= 1) {
            unsigned u = __shfl_up(s, off, 64);
            if (lane >= off) s += u;
        }
        if (lane == 63) wsum[wid] = s;
        __syncthreads();
        unsigned base = 0;
        for (unsigned w = 0; w < wid; w++) base += wsum[w];
        unsigned excl = base + s - local;
        unsigned kRem = s_kr;
        __syncthreads();
        if (kRem >= excl && kRem < excl + local) {
            if (P == 2) {
                if (kRem < excl + c0) { s_pref = (pref << bits) | (unsigned)(t * 2);     s_kr = kRem - excl; }
                else                  { s_pref = (pref << bits) | (unsigned)(t * 2 + 1); s_kr = kRem - excl - c0; }
            } else {
                s_pref = (pref << bits) | (unsigned)t;
                s_kr = kRem - excl;
            }
        }
        __syncthreads();
    }
    if (t == 0) st->median = u2f(s_pref);
}

// -------- fused threshold + 7x7 maxpool (pad=-inf) + binarize + multiply ----
// Fully vectorized LDS (b128 everywhere) with 2-way-only bank strides.
// th cc-space: col cc = gx - (bx*64 - 4), cc in [0,72) staged; every 4-col
// block is entirely in- or out-of-image (everything 4-aligned), so staging is
// pure aligned float4. LDS = 70*76*4 + 70*68*4 = 40320 B -> 4 blocks/CU.
__global__ __launch_bounds__(512, 8) void nms_kernel(
    const float* __restrict__ x, float* __restrict__ out,
    const SelState* __restrict__ st)
{
    __shared__ float th[TW * THS];   // 21.3 KB
    __shared__ float hm[TW * HMS];   // 19.0 KB

    const float med = st->median;
    const float NEGINF = -__builtin_inff();
    const int bx = blockIdx.x, by = blockIdx.y;
    const int gy0 = by * TS - HALO;       // x-row of th row 0
    const int gxbase = bx * TS - 4;       // x-col of th cc 0

    // stage: 70 rows x 18 aligned float4
    for (int task = threadIdx.x; task < TW * 18; task += 512) {
        int r = task / 18, q = task - r * 18;
        int gy = gy0 + r;
        int gxb = gxbase + q * 4;
        float4 v;
        if (gy >= 0 && gy < IMG_H && gxb >= 0 && gxb < IMG_W) {
            v = *(const float4*)&x[gy * IMG_W + gxb];
            v.x = (v.x < med) ? 0.0f : v.x;
            v.y = (v.y < med) ? 0.0f : v.y;
            v.z = (v.z < med) ? 0.0f : v.z;
            v.w = (v.w < med) ? 0.0f : v.w;
        } else {
            v = make_float4(NEGINF, NEGINF, NEGINF, NEGINF);
        }
        *(float4*)&th[r * THS + q * 4] = v;
    }
    __syncthreads();

    // horizontal 7-max: 560 tasks = 70 rows x 8 chunks of 8 outputs.
    // output col cout (x-col bx*64+cout) = max over cc (cout+1)..(cout+7).
    for (int task = threadIdx.x; task < TW * 8; task += 512) {
        int r = task % TW;              // lane-linear r: stride 76 -> 2-way only
        int c0 = (task / TW) * 8;
        float f[16];
        *(float4*)&f[0]  = *(const float4*)&th[r * THS + c0];
        *(float4*)&f[4]  = *(const float4*)&th[r * THS + c0 + 4];
        *(float4*)&f[8]  = *(const float4*)&th[r * THS + c0 + 8];
        *(float4*)&f[12] = *(const float4*)&th[r * THS + c0 + 12];
        float o[8];
        #pragma unroll
        for (int i = 0; i < 8; i++) {
            float m = f[i + 1];
            #pragma unroll
            for (int k = 2; k <= 7; k++) m = fmaxf(m, f[i + k]);
            o[i] = m;
        }
        *(float4*)&hm[r * HMS + c0]     = make_float4(o[0], o[1], o[2], o[3]);
        *(float4*)&hm[r * HMS + c0 + 4] = make_float4(o[4], o[5], o[6], o[7]);
    }
    __syncthreads();

    // vertical 7-max + binarize*x: 512 tasks = 16 col-groups x 32 row-pairs.
    {
        const int cg  = threadIdx.x & 15;          // 4-col group
        const int rr0 = (threadIdx.x >> 4) * 2;    // 2 output rows
        const int cb  = cg * 4;

        float4 h0  = *(const float4*)&hm[(rr0 + 0) * HMS + cb];
        float4 mid = *(const float4*)&hm[(rr0 + 1) * HMS + cb];
        #pragma unroll
        for (int i = 2; i <= 6; i++) {
            float4 hi = *(const float4*)&hm[(rr0 + i) * HMS + cb];
            mid.x = fmaxf(mid.x, hi.x); mid.y = fmaxf(mid.y, hi.y);
            mid.z = fmaxf(mid.z, hi.z); mid.w = fmaxf(mid.w, hi.w);
        }
        float4 h7 = *(const float4*)&hm[(rr0 + 7) * HMS + cb];

        #pragma unroll
        for (int k = 0; k < 2; k++) {
            int R = rr0 + k;
            float4 e = (k == 0) ? h0 : h7;
            float m4[4];
            m4[0] = fmaxf(mid.x, e.x); m4[1] = fmaxf(mid.y, e.y);
            m4[2] = fmaxf(mid.z, e.z); m4[3] = fmaxf(mid.w, e.w);
            // center th: cc = cout + 4 = cb+4.. -> aligned float4
            float4 t4 = *(const float4*)&th[(R + HALO) * THS + cb + 4];
            float tt[4] = {t4.x, t4.y, t4.z, t4.w};
            int gy = by * TS + R;
            int gx = bx * TS + cb;
            float o4[4];
            #pragma unroll
            for (int c = 0; c < 4; c++) {
                float o = 0.0f;
                if (tt[c] == m4[c]) {
                    // tt!=0: tt IS original x. tt==0: whole window sub-median
                    // (rare) -> reread x to preserve sign/value.
                    o = (tt[c] != 0.0f) ? tt[c] : x[gy * IMG_W + gx + c];
                }
                o4[c] = o;
            }
            *(float4*)&out[gy * IMG_W + gx] =
                make_float4(o4[0], o4[1], o4[2], o4[3]);
        }
    }
}

extern "C" void kernel_launch(void* const* d_in, const int* in_sizes, int n_in,
                              void* d_out, int out_size, void* d_ws, size_t ws_size,
                              hipStream_t stream)
{
    const float* x = (const float*)d_in[0];
    float* out = (float*)d_out;
    const int n = in_sizes[0];                  // 16777216
    const unsigned K = (unsigned)((n - 1) / 2); // rank of lower-middle element

    char* ws = (char*)d_ws;
    unsigned* cntA     = (unsigned*)ws;                 // 4 B (only memset)
    SelState* st       = (SelState*)(ws + 16);          // flag always written
    unsigned* belowArr = (unsigned*)(ws + 256);         // [CBLK], fully rewritten
    unsigned* candA    = (unsigned*)(ws + ws_size / 2); // 16 MB region

    hipMemsetAsync(cntA, 0, 4, stream);

    const int n4 = n / 4;
    count_compact<<<CBLK, 512, 0, stream>>>((const float4*)x, n4, belowArr, candA, cntA);
    finalize_kernel<<<1, 1024, 0, stream>>>(belowArr, candA, cntA, K, st);
    // exact single-kernel fallback: no-op when flag==1 (candB = d_out scratch)
    fb_exact<<<1, 1024, 0, stream>>>((const float4*)x, n4, K, (unsigned*)d_out, st);

    dim3 fg(IMG_W / TS, IMG_H / TS);
    nms_kernel<<<fg, 512, 0, stream>>>(x, out, st);
}